// Round 1
// baseline (1314.194 us; speedup 1.0000x reference)
//
#include <hip/hip_runtime.h>
#include <hip/hip_bf16.h>
#include <cstdint>
#include <cstddef>

// Problem constants
#define NB 64      // batch
#define NT 256     // time steps
#define NL 64      // links
#define NH 128     // hidden
#define NN 16384   // nodes = NB*NT
#define NE 524288  // edges
#define NG 512     // 4*NH gates
#define NOUT 768   // 12*NL

// ---------------- small prep kernels ----------------

// Wt[n][k] = W[k][n], W is [K, Nout] row-major
__global__ __launch_bounds__(256) void k_transpose(const float* __restrict__ W,
                                                   float* __restrict__ Wt,
                                                   int K, int Nout) {
  int i = blockIdx.x * 256 + threadIdx.x;
  if (i < K * Nout) {
    int k = i / Nout, n = i % Nout;
    Wt[n * K + k] = W[i];
  }
}

// dvec[j] = sum_m dist[m] * W0[(64+m)*128 + j]   (128 blocks, one per j)
__global__ __launch_bounds__(256) void k_dvec(const float* __restrict__ dist,
                                              const float* __restrict__ W0,
                                              float* __restrict__ dvec) {
  __shared__ float red[256];
  int j = blockIdx.x;
  int t = threadIdx.x;
  float acc = 0.f;
  for (int m = t; m < 4096; m += 256)
    acc += dist[m] * W0[(size_t)(64 + m) * 128 + j];
  red[t] = acc;
  __syncthreads();
  for (int off = 128; off > 0; off >>= 1) {
    if (t < off) red[t] += red[t + off];
    __syncthreads();
  }
  if (t == 0) dvec[j] = red[0];
}

__global__ __launch_bounds__(256) void k_count(const int* __restrict__ dst,
                                               int* __restrict__ counts) {
  int i = blockIdx.x * 256 + threadIdx.x;
  atomicAdd(&counts[dst[i]], 1);
}

__global__ __launch_bounds__(256) void k_dinv(const int* __restrict__ counts,
                                              float* __restrict__ dinv) {
  int n = blockIdx.x * 256 + threadIdx.x;
  dinv[n] = rsqrtf((float)counts[n] + 1.0f);
}

// exclusive scan of counts[16384] -> rowstart[16385]; single block of 1024
__global__ __launch_bounds__(1024) void k_scan(const int* __restrict__ counts,
                                               int* __restrict__ rowstart) {
  __shared__ int part[1024];
  int t = threadIdx.x;
  int base = t * 16;
  int local[16];
  int s = 0;
#pragma unroll
  for (int i = 0; i < 16; i++) { local[i] = s; s += counts[base + i]; }
  part[t] = s;
  __syncthreads();
  for (int off = 1; off < 1024; off <<= 1) {
    int v = (t >= off) ? part[t - off] : 0;
    __syncthreads();
    part[t] += v;
    __syncthreads();
  }
  int prefix = (t == 0) ? 0 : part[t - 1];
#pragma unroll
  for (int i = 0; i < 16; i++) rowstart[base + i] = prefix + local[i];
  if (t == 1023) rowstart[16384] = part[1023];
}

__global__ __launch_bounds__(256) void k_fill(const int* __restrict__ src,
                                              const int* __restrict__ dst,
                                              const int* __restrict__ rowstart,
                                              int* __restrict__ fill,
                                              const float* __restrict__ dinv,
                                              int* __restrict__ csr_src,
                                              float* __restrict__ csr_nrm) {
  int e = blockIdx.x * 256 + threadIdx.x;
  int sN = src[e], dN = dst[e];
  int pos = rowstart[dN] + atomicAdd(&fill[dN], 1);
  csr_src[pos] = sN;
  csr_nrm[pos] = dinv[sN] * dinv[dN];
}

// ---------------- GEMM: C[M,Nn] = A[M,K] * B[Nn,K]^T (+bias0+bias1)(+relu) ----------------
// grid (M/64, Nn/64), block 256. K = 64 or 128.
template <int K, bool RELU>
__global__ __launch_bounds__(256) void k_gemm_abt(const float* __restrict__ A,
                                                  const float* __restrict__ Bm,
                                                  const float* __restrict__ bias0,
                                                  const float* __restrict__ bias1,
                                                  float* __restrict__ C, int Nn) {
  __shared__ float As[64][K + 1];
  __shared__ float Bs[64][K + 1];
  const int tid = threadIdx.x;
  const int bm = blockIdx.x, bn = blockIdx.y;
  const int VPR = K / 4;  // float4 per row
  for (int i = tid; i < 64 * VPR; i += 256) {
    int r = i / VPR, v = (i % VPR) * 4;
    float4 q = *(const float4*)(A + (size_t)(bm * 64 + r) * K + v);
    As[r][v] = q.x; As[r][v + 1] = q.y; As[r][v + 2] = q.z; As[r][v + 3] = q.w;
  }
  for (int i = tid; i < 64 * VPR; i += 256) {
    int r = i / VPR, v = (i % VPR) * 4;
    float4 q = *(const float4*)(Bm + (size_t)(bn * 64 + r) * K + v);
    Bs[r][v] = q.x; Bs[r][v + 1] = q.y; Bs[r][v + 2] = q.z; Bs[r][v + 3] = q.w;
  }
  __syncthreads();
  const int tr = (tid >> 4) << 2;   // output rows tr..tr+3
  const int tc = (tid & 15) << 2;   // output cols tc..tc+3
  float acc[4][4] = {};
#pragma unroll 4
  for (int k = 0; k < K; k++) {
    float a0 = As[tr + 0][k], a1 = As[tr + 1][k], a2 = As[tr + 2][k], a3 = As[tr + 3][k];
    float b0 = Bs[tc + 0][k], b1 = Bs[tc + 1][k], b2 = Bs[tc + 2][k], b3 = Bs[tc + 3][k];
    acc[0][0] += a0 * b0; acc[0][1] += a0 * b1; acc[0][2] += a0 * b2; acc[0][3] += a0 * b3;
    acc[1][0] += a1 * b0; acc[1][1] += a1 * b1; acc[1][2] += a1 * b2; acc[1][3] += a1 * b3;
    acc[2][0] += a2 * b0; acc[2][1] += a2 * b1; acc[2][2] += a2 * b2; acc[2][3] += a2 * b3;
    acc[3][0] += a3 * b0; acc[3][1] += a3 * b1; acc[3][2] += a3 * b2; acc[3][3] += a3 * b3;
  }
#pragma unroll
  for (int i2 = 0; i2 < 4; i2++) {
    int row = bm * 64 + tr + i2;
#pragma unroll
    for (int j2 = 0; j2 < 4; j2++) {
      int col = bn * 64 + tc + j2;
      float v = acc[i2][j2];
      if (bias0) v += bias0[col];
      if (bias1) v += bias1[col];
      if (RELU) v = fmaxf(v, 0.f);
      C[(size_t)row * Nn + col] = v;
    }
  }
}

// ---------------- GCN aggregation: out = relu(D^-1/2 A D^-1/2 h + dinv^2*h + b) ----------------
// one wave per node; lane handles dims lane and lane+64
__global__ __launch_bounds__(256) void k_agg(const float* __restrict__ h,
                                             const int* __restrict__ rowstart,
                                             const int* __restrict__ csr_src,
                                             const float* __restrict__ csr_nrm,
                                             const float* __restrict__ dinv,
                                             const float* __restrict__ bias,
                                             float* __restrict__ out) {
  int node = blockIdx.x * 4 + (threadIdx.x >> 6);
  int lane = threadIdx.x & 63;
  int s = rowstart[node], e = rowstart[node + 1];
  float a0 = 0.f, a1 = 0.f;
  for (int p = s; p < e; p++) {
    int src = csr_src[p];
    float w = csr_nrm[p];
    a0 += h[(size_t)src * 128 + lane] * w;
    a1 += h[(size_t)src * 128 + 64 + lane] * w;
  }
  float di = dinv[node];
  float sw = di * di;
  a0 += h[(size_t)node * 128 + lane] * sw + bias[lane];
  a1 += h[(size_t)node * 128 + 64 + lane] * sw + bias[64 + lane];
  out[(size_t)node * 128 + lane] = fmaxf(a0, 0.f);
  out[(size_t)node * 128 + 64 + lane] = fmaxf(a1, 0.f);
}

// ---------------- LSTM recurrence: one block per batch element ----------------
// pre[n][j] already contains x@Wih^T + bih + bhh. 512 threads, thread j owns gate j.
template <bool LAST_ONLY>
__global__ __launch_bounds__(512) void k_lstm(const float* __restrict__ pre,
                                              const float* __restrict__ Whh,
                                              float* __restrict__ yout) {
  __shared__ float hbuf[128];
  __shared__ float gbuf[512];
  const int b = blockIdx.x;
  const int j = threadIdx.x;
  float wv[128];
#pragma unroll
  for (int k = 0; k < 128; k++) wv[k] = Whh[(size_t)j * 128 + k];
  float c = 0.f;
  if (j < 128) hbuf[j] = 0.f;
  __syncthreads();
  for (int t = 0; t < 256; t++) {
    float acc = pre[((size_t)b * 256 + t) * 512 + j];
#pragma unroll
    for (int k4 = 0; k4 < 32; k4++) {
      float4 h4 = *(const float4*)(&hbuf[k4 * 4]);
      acc += wv[4 * k4 + 0] * h4.x + wv[4 * k4 + 1] * h4.y +
             wv[4 * k4 + 2] * h4.z + wv[4 * k4 + 3] * h4.w;
    }
    gbuf[j] = acc;
    __syncthreads();
    if (j < 128) {
      float gi = gbuf[j], gf = gbuf[j + 128], gg = gbuf[j + 256], go = gbuf[j + 384];
      float si = 1.f / (1.f + __expf(-gi));
      float sf = 1.f / (1.f + __expf(-gf));
      float so = 1.f / (1.f + __expf(-go));
      float tg = tanhf(gg);
      c = sf * c + si * tg;
      float hn = so * tanhf(c);
      hbuf[j] = hn;
      if (!LAST_ONLY) {
        yout[((size_t)b * 256 + t) * 128 + j] = hn;
      } else if (t == 255) {
        yout[(size_t)b * 128 + j] = hn;
      }
    }
    __syncthreads();
  }
}

// ---------------- host ----------------

extern "C" void kernel_launch(void* const* d_in, const int* in_sizes, int n_in,
                              void* d_out, int out_size, void* d_ws, size_t ws_size,
                              hipStream_t stream) {
  const float* x    = (const float*)d_in[0];   // [64,256,64] -> [16384,64]
  const float* dist = (const float*)d_in[1];   // [64,64]
  const int*   ei   = (const int*)d_in[2];     // [2, 524288]
  const float* W0   = (const float*)d_in[3];   // [4160,128]
  const float* b0   = (const float*)d_in[4];
  const float* W1   = (const float*)d_in[5];   // [128,128]
  const float* b1   = (const float*)d_in[6];
  const float* W2   = (const float*)d_in[7];
  const float* b2   = (const float*)d_in[8];
  const float* Wih0 = (const float*)d_in[9];   // [512,128]
  const float* Whh0 = (const float*)d_in[10];  // [512,128]
  const float* bih0 = (const float*)d_in[11];
  const float* bhh0 = (const float*)d_in[12];
  const float* Wih1 = (const float*)d_in[13];
  const float* Whh1 = (const float*)d_in[14];
  const float* bih1 = (const float*)d_in[15];
  const float* bhh1 = (const float*)d_in[16];
  const float* fcW  = (const float*)d_in[17];  // [768,128]
  const float* fcb  = (const float*)d_in[18];
  float* out = (float*)d_out;

  char* ws = (char*)d_ws;
  size_t off = 0;
  auto alloc = [&](size_t bytes) -> void* {
    void* p = ws + off;
    off += (bytes + 255) & ~(size_t)255;
    return p;
  };
  float* bufA     = (float*)alloc((size_t)NN * 128 * 4);
  float* bufB     = (float*)alloc((size_t)NN * 128 * 4);
  float* pre      = (float*)alloc((size_t)NN * 512 * 4);
  int*   csr_src  = (int*)alloc((size_t)NE * 4);
  float* csr_nrm  = (float*)alloc((size_t)NE * 4);
  int*   counts   = (int*)alloc((size_t)NN * 4);
  int*   fillc    = (int*)alloc((size_t)NN * 4);
  int*   rowstart = (int*)alloc((size_t)(NN + 1) * 4);
  float* dinv     = (float*)alloc((size_t)NN * 4);
  float* dvec     = (float*)alloc(128 * 4);
  float* hlast    = (float*)alloc(64 * 128 * 4);
  float* wt0      = (float*)alloc(128 * 64 * 4);
  float* wt1      = (float*)alloc(128 * 128 * 4);
  float* wt2      = (float*)alloc(128 * 128 * 4);
  (void)ws_size; (void)in_sizes; (void)n_in; (void)out_size;

  const int* srcIdx = ei;
  const int* dstIdx = ei + NE;

  hipMemsetAsync(counts, 0, (size_t)NN * 4, stream);
  hipMemsetAsync(fillc, 0, (size_t)NN * 4, stream);

  // weight transposes + distance vector
  k_transpose<<<(64 * 128 + 255) / 256, 256, 0, stream>>>(W0, wt0, 64, 128);
  k_transpose<<<(128 * 128 + 255) / 256, 256, 0, stream>>>(W1, wt1, 128, 128);
  k_transpose<<<(128 * 128 + 255) / 256, 256, 0, stream>>>(W2, wt2, 128, 128);
  k_dvec<<<128, 256, 0, stream>>>(dist, W0, dvec);

  // CSR build (reused by all 3 GCN layers)
  k_count<<<NE / 256, 256, 0, stream>>>(dstIdx, counts);
  k_scan<<<1, 1024, 0, stream>>>(counts, rowstart);
  k_dinv<<<NN / 256, 256, 0, stream>>>(counts, dinv);
  k_fill<<<NE / 256, 256, 0, stream>>>(srcIdx, dstIdx, rowstart, fillc, dinv,
                                       csr_src, csr_nrm);

  // GCN layer 0: h0 = x @ W0a^T + dvec  (bias/relu happen after aggregation)
  dim3 gH(NN / 64, 128 / 64);
  k_gemm_abt<64, false><<<gH, 256, 0, stream>>>(x, wt0, dvec, nullptr, bufB, 128);
  k_agg<<<NN / 4, 256, 0, stream>>>(bufB, rowstart, csr_src, csr_nrm, dinv, b0, bufA);
  // GCN layer 1
  k_gemm_abt<128, false><<<gH, 256, 0, stream>>>(bufA, wt1, nullptr, nullptr, bufB, 128);
  k_agg<<<NN / 4, 256, 0, stream>>>(bufB, rowstart, csr_src, csr_nrm, dinv, b1, bufA);
  // GCN layer 2
  k_gemm_abt<128, false><<<gH, 256, 0, stream>>>(bufA, wt2, nullptr, nullptr, bufB, 128);
  k_agg<<<NN / 4, 256, 0, stream>>>(bufB, rowstart, csr_src, csr_nrm, dinv, b2, bufA);

  // LSTM layer 0: pre = feat @ Wih0^T + bih0 + bhh0 ; recurrence -> y1 (bufB)
  dim3 gP(NN / 64, 512 / 64);
  k_gemm_abt<128, false><<<gP, 256, 0, stream>>>(bufA, Wih0, bih0, bhh0, pre, 512);
  k_lstm<false><<<64, 512, 0, stream>>>(pre, Whh0, bufB);
  // LSTM layer 1
  k_gemm_abt<128, false><<<gP, 256, 0, stream>>>(bufB, Wih1, bih1, bhh1, pre, 512);
  k_lstm<true><<<64, 512, 0, stream>>>(pre, Whh1, hlast);

  // FC: out[64,768] = hlast @ fcW^T + fcb
  dim3 gF(1, NOUT / 64);
  k_gemm_abt<128, false><<<gF, 256, 0, stream>>>(hlast, fcW, fcb, nullptr, out, NOUT);
}

// Round 2
// 912.290 us; speedup vs baseline: 1.4405x; 1.4405x over previous
//
#include <hip/hip_runtime.h>
#include <hip/hip_bf16.h>
#include <cstdint>
#include <cstddef>

// Problem constants
#define NB 64      // batch
#define NT 256     // time steps
#define NL 64      // links
#define NH 128     // hidden
#define NN 16384   // nodes = NB*NT
#define NE 524288  // edges
#define NG 512     // 4*NH gates
#define NOUT 768   // 12*NL

// ---------------- small prep kernels ----------------

// Wt[n][k] = W[k][n], W is [K, Nout] row-major
__global__ __launch_bounds__(256) void k_transpose(const float* __restrict__ W,
                                                   float* __restrict__ Wt,
                                                   int K, int Nout) {
  int i = blockIdx.x * 256 + threadIdx.x;
  if (i < K * Nout) {
    int k = i / Nout, n = i % Nout;
    Wt[n * K + k] = W[i];
  }
}

// dvec[j] = sum_m dist[m] * W0[(64+m)*128 + j]   (128 blocks, one per j)
__global__ __launch_bounds__(256) void k_dvec(const float* __restrict__ dist,
                                              const float* __restrict__ W0,
                                              float* __restrict__ dvec) {
  __shared__ float red[256];
  int j = blockIdx.x;
  int t = threadIdx.x;
  float acc = 0.f;
  for (int m = t; m < 4096; m += 256)
    acc += dist[m] * W0[(size_t)(64 + m) * 128 + j];
  red[t] = acc;
  __syncthreads();
  for (int off = 128; off > 0; off >>= 1) {
    if (t < off) red[t] += red[t + off];
    __syncthreads();
  }
  if (t == 0) dvec[j] = red[0];
}

__global__ __launch_bounds__(256) void k_count(const int* __restrict__ dst,
                                               int* __restrict__ counts) {
  int i = blockIdx.x * 256 + threadIdx.x;
  atomicAdd(&counts[dst[i]], 1);
}

__global__ __launch_bounds__(256) void k_dinv(const int* __restrict__ counts,
                                              float* __restrict__ dinv) {
  int n = blockIdx.x * 256 + threadIdx.x;
  dinv[n] = rsqrtf((float)counts[n] + 1.0f);
}

// exclusive scan of counts[16384] -> rowstart[16385]; single block of 1024
__global__ __launch_bounds__(1024) void k_scan(const int* __restrict__ counts,
                                               int* __restrict__ rowstart) {
  __shared__ int part[1024];
  int t = threadIdx.x;
  int base = t * 16;
  int local[16];
  int s = 0;
#pragma unroll
  for (int i = 0; i < 16; i++) { local[i] = s; s += counts[base + i]; }
  part[t] = s;
  __syncthreads();
  for (int off = 1; off < 1024; off <<= 1) {
    int v = (t >= off) ? part[t - off] : 0;
    __syncthreads();
    part[t] += v;
    __syncthreads();
  }
  int prefix = (t == 0) ? 0 : part[t - 1];
#pragma unroll
  for (int i = 0; i < 16; i++) rowstart[base + i] = prefix + local[i];
  if (t == 1023) rowstart[16384] = part[1023];
}

__global__ __launch_bounds__(256) void k_fill(const int* __restrict__ src,
                                              const int* __restrict__ dst,
                                              const int* __restrict__ rowstart,
                                              int* __restrict__ fill,
                                              const float* __restrict__ dinv,
                                              int* __restrict__ csr_src,
                                              float* __restrict__ csr_nrm) {
  int e = blockIdx.x * 256 + threadIdx.x;
  int sN = src[e], dN = dst[e];
  int pos = rowstart[dN] + atomicAdd(&fill[dN], 1);
  csr_src[pos] = sN;
  csr_nrm[pos] = dinv[sN] * dinv[dN];
}

// ---------------- GEMM: C[M,Nn] = A[M,K] * B[Nn,K]^T (+bias0+bias1) ----------------
// grid (M/64, Nn/64), block 256. K = 64 or 128.
// PERMC: store col' = (col&127)*4 + (col>>7)  (gate-interleaved layout for LSTM pre)
template <int K, bool RELU, bool PERMC = false>
__global__ __launch_bounds__(256) void k_gemm_abt(const float* __restrict__ A,
                                                  const float* __restrict__ Bm,
                                                  const float* __restrict__ bias0,
                                                  const float* __restrict__ bias1,
                                                  float* __restrict__ C, int Nn) {
  __shared__ float As[64][K + 1];
  __shared__ float Bs[64][K + 1];
  const int tid = threadIdx.x;
  const int bm = blockIdx.x, bn = blockIdx.y;
  const int VPR = K / 4;  // float4 per row
  for (int i = tid; i < 64 * VPR; i += 256) {
    int r = i / VPR, v = (i % VPR) * 4;
    float4 q = *(const float4*)(A + (size_t)(bm * 64 + r) * K + v);
    As[r][v] = q.x; As[r][v + 1] = q.y; As[r][v + 2] = q.z; As[r][v + 3] = q.w;
  }
  for (int i = tid; i < 64 * VPR; i += 256) {
    int r = i / VPR, v = (i % VPR) * 4;
    float4 q = *(const float4*)(Bm + (size_t)(bn * 64 + r) * K + v);
    Bs[r][v] = q.x; Bs[r][v + 1] = q.y; Bs[r][v + 2] = q.z; Bs[r][v + 3] = q.w;
  }
  __syncthreads();
  const int tr = (tid >> 4) << 2;   // output rows tr..tr+3
  const int tc = (tid & 15) << 2;   // output cols tc..tc+3
  float acc[4][4] = {};
#pragma unroll 4
  for (int k = 0; k < K; k++) {
    float a0 = As[tr + 0][k], a1 = As[tr + 1][k], a2 = As[tr + 2][k], a3 = As[tr + 3][k];
    float b0 = Bs[tc + 0][k], b1 = Bs[tc + 1][k], b2 = Bs[tc + 2][k], b3 = Bs[tc + 3][k];
    acc[0][0] += a0 * b0; acc[0][1] += a0 * b1; acc[0][2] += a0 * b2; acc[0][3] += a0 * b3;
    acc[1][0] += a1 * b0; acc[1][1] += a1 * b1; acc[1][2] += a1 * b2; acc[1][3] += a1 * b3;
    acc[2][0] += a2 * b0; acc[2][1] += a2 * b1; acc[2][2] += a2 * b2; acc[2][3] += a2 * b3;
    acc[3][0] += a3 * b0; acc[3][1] += a3 * b1; acc[3][2] += a3 * b2; acc[3][3] += a3 * b3;
  }
#pragma unroll
  for (int i2 = 0; i2 < 4; i2++) {
    int row = bm * 64 + tr + i2;
#pragma unroll
    for (int j2 = 0; j2 < 4; j2++) {
      int col = bn * 64 + tc + j2;
      float v = acc[i2][j2];
      if (bias0) v += bias0[col];
      if (bias1) v += bias1[col];
      if (RELU) v = fmaxf(v, 0.f);
      int colw = PERMC ? ((col & 127) * 4 + (col >> 7)) : col;
      C[(size_t)row * Nn + colw] = v;
    }
  }
}

// ---------------- GCN aggregation ----------------
__global__ __launch_bounds__(256) void k_agg(const float* __restrict__ h,
                                             const int* __restrict__ rowstart,
                                             const int* __restrict__ csr_src,
                                             const float* __restrict__ csr_nrm,
                                             const float* __restrict__ dinv,
                                             const float* __restrict__ bias,
                                             float* __restrict__ out) {
  int node = blockIdx.x * 4 + (threadIdx.x >> 6);
  int lane = threadIdx.x & 63;
  int s = rowstart[node], e = rowstart[node + 1];
  float a0 = 0.f, a1 = 0.f;
  for (int p = s; p < e; p++) {
    int src = csr_src[p];
    float w = csr_nrm[p];
    a0 += h[(size_t)src * 128 + lane] * w;
    a1 += h[(size_t)src * 128 + 64 + lane] * w;
  }
  float di = dinv[node];
  float sw = di * di;
  a0 += h[(size_t)node * 128 + lane] * sw + bias[lane];
  a1 += h[(size_t)node * 128 + 64 + lane] * sw + bias[64 + lane];
  out[(size_t)node * 128 + lane] = fmaxf(a0, 0.f);
  out[(size_t)node * 128 + 64 + lane] = fmaxf(a1, 0.f);
}

// ---------------- LSTM recurrence, quad-per-unit with DPP K-reduction ----------------
// 512 threads = 128 quads. Quad u owns unit u (all 4 gates); lane c of quad covers
// k in [32c, 32c+32). Weights (4 gates x 8 float4) live in 128 VGPRs.
// pre is in permuted layout P'[n][u*4+g], so per-step bias load = pre[n*512+tid].

template <int CTRL>
__device__ __forceinline__ float dppadd(float x) {
  int r = __builtin_amdgcn_update_dpp(0, __float_as_int(x), CTRL, 0xF, 0xF, true);
  return x + __int_as_float(r);
}
// quad_perm[1,0,3,2] = 0xB1 (xor1), quad_perm[2,3,0,1] = 0x4E (xor2)

__device__ __forceinline__ float sigf(float x) {
  return 1.f / (1.f + __expf(-x));
}
__device__ __forceinline__ float tanhf_fast(float x) {
  return 1.f - 2.f / (__expf(2.f * x) + 1.f);
}

template <bool LAST_ONLY>
__global__ __launch_bounds__(512, 2) void k_lstm2(const float* __restrict__ pre,
                                                  const float* __restrict__ Whh,
                                                  float* __restrict__ yout) {
  __shared__ float hbuf[2][128];
  const int tid = threadIdx.x;
  const int b = blockIdx.x;
  const int c4 = tid & 3;   // k-quarter
  const int u = tid >> 2;   // hidden unit 0..127

  // slot rotation: float4 index within h = c4*8 + ((u + 2*c4 + j) & 7)
  // the 2*c4 skew makes the quad's 4 segment reads bank-disjoint.
  int hidx[8];
#pragma unroll
  for (int j = 0; j < 8; j++) hidx[j] = c4 * 8 + (((u & 7) + 2 * c4 + j) & 7);

  // weight fragments: Wv[g][j] = Whh[g*128+u][4*hidx[j] .. +3]
  float4 Wv[4][8];
#pragma unroll
  for (int g = 0; g < 4; g++)
#pragma unroll
    for (int j = 0; j < 8; j++)
      Wv[g][j] = *(const float4*)(Whh + (size_t)(g * 128 + u) * 128 + hidx[j] * 4);

  if (tid < 128) hbuf[0][tid] = 0.f;
  float cs = 0.f;
  const float* preb = pre + (size_t)b * 256 * 512 + tid;
  float pcur = preb[0];
  __syncthreads();

#define LSTM_STEP(CUR, NXT, T)                                                 \
  {                                                                            \
    int tn = (T) + 1; if (tn > 255) tn = 255;                                  \
    float pnext = preb[(size_t)tn * 512];                                      \
    const float4* hp = (const float4*)&hbuf[CUR][0];                           \
    float a0 = (c4 == 0) ? pcur : 0.f;                                         \
    float a1 = (c4 == 1) ? pcur : 0.f;                                         \
    float a2 = (c4 == 2) ? pcur : 0.f;                                         \
    float a3 = (c4 == 3) ? pcur : 0.f;                                         \
    _Pragma("unroll")                                                          \
    for (int j = 0; j < 8; j++) {                                              \
      float4 hv = hp[hidx[j]];                                                 \
      float4 w0 = Wv[0][j], w1 = Wv[1][j], w2 = Wv[2][j], w3 = Wv[3][j];       \
      a0 = fmaf(w0.x, hv.x, a0); a0 = fmaf(w0.y, hv.y, a0);                    \
      a0 = fmaf(w0.z, hv.z, a0); a0 = fmaf(w0.w, hv.w, a0);                    \
      a1 = fmaf(w1.x, hv.x, a1); a1 = fmaf(w1.y, hv.y, a1);                    \
      a1 = fmaf(w1.z, hv.z, a1); a1 = fmaf(w1.w, hv.w, a1);                    \
      a2 = fmaf(w2.x, hv.x, a2); a2 = fmaf(w2.y, hv.y, a2);                    \
      a2 = fmaf(w2.z, hv.z, a2); a2 = fmaf(w2.w, hv.w, a2);                    \
      a3 = fmaf(w3.x, hv.x, a3); a3 = fmaf(w3.y, hv.y, a3);                    \
      a3 = fmaf(w3.z, hv.z, a3); a3 = fmaf(w3.w, hv.w, a3);                    \
    }                                                                          \
    a0 = dppadd<0xB1>(a0); a0 = dppadd<0x4E>(a0);                              \
    a1 = dppadd<0xB1>(a1); a1 = dppadd<0x4E>(a1);                              \
    a2 = dppadd<0xB1>(a2); a2 = dppadd<0x4E>(a2);                              \
    a3 = dppadd<0xB1>(a3); a3 = dppadd<0x4E>(a3);                              \
    float si = sigf(a0), sf = sigf(a1), tg = tanhf_fast(a2), so = sigf(a3);    \
    cs = sf * cs + si * tg;                                                    \
    float hnew = so * tanhf_fast(cs);                                          \
    if (c4 == 0) hbuf[NXT][u] = hnew;                                          \
    if (!LAST_ONLY) {                                                          \
      if (c4 == 1) yout[((size_t)b * 256 + (T)) * 128 + u] = hnew;             \
    } else if ((T) == 255) {                                                   \
      if (c4 == 1) yout[(size_t)b * 128 + u] = hnew;                           \
    }                                                                          \
    pcur = pnext;                                                              \
    __syncthreads();                                                           \
  }

  for (int t = 0; t < 256; t += 2) {
    LSTM_STEP(0, 1, t);
    LSTM_STEP(1, 0, t + 1);
  }
#undef LSTM_STEP
}

// ---------------- host ----------------

extern "C" void kernel_launch(void* const* d_in, const int* in_sizes, int n_in,
                              void* d_out, int out_size, void* d_ws, size_t ws_size,
                              hipStream_t stream) {
  const float* x    = (const float*)d_in[0];   // [64,256,64] -> [16384,64]
  const float* dist = (const float*)d_in[1];   // [64,64]
  const int*   ei   = (const int*)d_in[2];     // [2, 524288]
  const float* W0   = (const float*)d_in[3];   // [4160,128]
  const float* b0   = (const float*)d_in[4];
  const float* W1   = (const float*)d_in[5];   // [128,128]
  const float* b1   = (const float*)d_in[6];
  const float* W2   = (const float*)d_in[7];
  const float* b2   = (const float*)d_in[8];
  const float* Wih0 = (const float*)d_in[9];   // [512,128]
  const float* Whh0 = (const float*)d_in[10];  // [512,128]
  const float* bih0 = (const float*)d_in[11];
  const float* bhh0 = (const float*)d_in[12];
  const float* Wih1 = (const float*)d_in[13];
  const float* Whh1 = (const float*)d_in[14];
  const float* bih1 = (const float*)d_in[15];
  const float* bhh1 = (const float*)d_in[16];
  const float* fcW  = (const float*)d_in[17];  // [768,128]
  const float* fcb  = (const float*)d_in[18];
  float* out = (float*)d_out;

  char* ws = (char*)d_ws;
  size_t off = 0;
  auto alloc = [&](size_t bytes) -> void* {
    void* p = ws + off;
    off += (bytes + 255) & ~(size_t)255;
    return p;
  };
  float* bufA     = (float*)alloc((size_t)NN * 128 * 4);
  float* bufB     = (float*)alloc((size_t)NN * 128 * 4);
  float* pre      = (float*)alloc((size_t)NN * 512 * 4);
  int*   csr_src  = (int*)alloc((size_t)NE * 4);
  float* csr_nrm  = (float*)alloc((size_t)NE * 4);
  int*   counts   = (int*)alloc((size_t)NN * 4);
  int*   fillc    = (int*)alloc((size_t)NN * 4);
  int*   rowstart = (int*)alloc((size_t)(NN + 1) * 4);
  float* dinv     = (float*)alloc((size_t)NN * 4);
  float* dvec     = (float*)alloc(128 * 4);
  float* hlast    = (float*)alloc(64 * 128 * 4);
  float* wt0      = (float*)alloc(128 * 64 * 4);
  float* wt1      = (float*)alloc(128 * 128 * 4);
  float* wt2      = (float*)alloc(128 * 128 * 4);
  (void)ws_size; (void)in_sizes; (void)n_in; (void)out_size;

  const int* srcIdx = ei;
  const int* dstIdx = ei + NE;

  hipMemsetAsync(counts, 0, (size_t)NN * 4, stream);
  hipMemsetAsync(fillc, 0, (size_t)NN * 4, stream);

  // weight transposes + distance vector
  k_transpose<<<(64 * 128 + 255) / 256, 256, 0, stream>>>(W0, wt0, 64, 128);
  k_transpose<<<(128 * 128 + 255) / 256, 256, 0, stream>>>(W1, wt1, 128, 128);
  k_transpose<<<(128 * 128 + 255) / 256, 256, 0, stream>>>(W2, wt2, 128, 128);
  k_dvec<<<128, 256, 0, stream>>>(dist, W0, dvec);

  // CSR build (reused by all 3 GCN layers)
  k_count<<<NE / 256, 256, 0, stream>>>(dstIdx, counts);
  k_scan<<<1, 1024, 0, stream>>>(counts, rowstart);
  k_dinv<<<NN / 256, 256, 0, stream>>>(counts, dinv);
  k_fill<<<NE / 256, 256, 0, stream>>>(srcIdx, dstIdx, rowstart, fillc, dinv,
                                       csr_src, csr_nrm);

  // GCN layer 0: h0 = x @ W0a^T + dvec  (bias/relu happen after aggregation)
  dim3 gH(NN / 64, 128 / 64);
  k_gemm_abt<64, false><<<gH, 256, 0, stream>>>(x, wt0, dvec, nullptr, bufB, 128);
  k_agg<<<NN / 4, 256, 0, stream>>>(bufB, rowstart, csr_src, csr_nrm, dinv, b0, bufA);
  // GCN layer 1
  k_gemm_abt<128, false><<<gH, 256, 0, stream>>>(bufA, wt1, nullptr, nullptr, bufB, 128);
  k_agg<<<NN / 4, 256, 0, stream>>>(bufB, rowstart, csr_src, csr_nrm, dinv, b1, bufA);
  // GCN layer 2
  k_gemm_abt<128, false><<<gH, 256, 0, stream>>>(bufA, wt2, nullptr, nullptr, bufB, 128);
  k_agg<<<NN / 4, 256, 0, stream>>>(bufB, rowstart, csr_src, csr_nrm, dinv, b2, bufA);

  // LSTM layer 0: pre (permuted) = feat @ Wih0^T + bih0 + bhh0 ; recurrence -> y1 (bufB)
  dim3 gP(NN / 64, 512 / 64);
  k_gemm_abt<128, false, true><<<gP, 256, 0, stream>>>(bufA, Wih0, bih0, bhh0, pre, 512);
  k_lstm2<false><<<64, 512, 0, stream>>>(pre, Whh0, bufB);
  // LSTM layer 1
  k_gemm_abt<128, false, true><<<gP, 256, 0, stream>>>(bufB, Wih1, bih1, bhh1, pre, 512);
  k_lstm2<true><<<64, 512, 0, stream>>>(pre, Whh1, hlast);

  // FC: out[64,768] = hlast @ fcW^T + fcb
  dim3 gF(1, NOUT / 64);
  k_gemm_abt<128, false><<<gF, 256, 0, stream>>>(hlast, fcW, fcb, nullptr, out, NOUT);
}